// Round 1
// baseline (181.842 us; speedup 1.0000x reference)
//
#include <hip/hip_runtime.h>

// CLIP text embeddings: out[0, s, :] = tok_w[input_ids[s], :] + pos_w[position_ids[s], :]
// S=77, D=768, fp32. 768 floats = 192 float4 per row.

#define D_MODEL 768
#define D_VEC4 (D_MODEL / 4)   // 192

__global__ void clip_embed_kernel(const int* __restrict__ input_ids,
                                  const int* __restrict__ position_ids,
                                  const float* __restrict__ tok_w,
                                  const float* __restrict__ pos_w,
                                  float* __restrict__ out) {
    const int s = blockIdx.x;        // sequence position
    const int d = threadIdx.x;       // float4 index within the row [0,192)

    const int tid = input_ids[s];
    const int pid = position_ids[s];

    const float4* t = reinterpret_cast<const float4*>(tok_w + (size_t)tid * D_MODEL);
    const float4* p = reinterpret_cast<const float4*>(pos_w + (size_t)pid * D_MODEL);
    float4* o = reinterpret_cast<float4*>(out + (size_t)s * D_MODEL);

    float4 a = t[d];
    float4 b = p[d];
    o[d] = make_float4(a.x + b.x, a.y + b.y, a.z + b.z, a.w + b.w);
}

extern "C" void kernel_launch(void* const* d_in, const int* in_sizes, int n_in,
                              void* d_out, int out_size, void* d_ws, size_t ws_size,
                              hipStream_t stream) {
    const int* input_ids    = (const int*)d_in[0];   // [77] int32
    const int* position_ids = (const int*)d_in[1];   // [77] int32
    const float* tok_w      = (const float*)d_in[2]; // [49408, 768] fp32
    const float* pos_w      = (const float*)d_in[3]; // [77, 768] fp32
    float* out              = (float*)d_out;         // [1, 77, 768] fp32

    const int seq_len = in_sizes[0];                 // 77
    clip_embed_kernel<<<seq_len, D_VEC4, 0, stream>>>(input_ids, position_ids,
                                                      tok_w, pos_w, out);
}